// Round 9
// baseline (201.478 us; speedup 1.0000x reference)
//
#include <hip/hip_runtime.h>
#include <hip/hip_bf16.h>
#include <stdint.h>

typedef unsigned short u16;
typedef unsigned int u32;
typedef short s16x8 __attribute__((ext_vector_type(8)));
typedef short s16x4 __attribute__((ext_vector_type(4)));
typedef float f32x4 __attribute__((ext_vector_type(4)));

#define MFMA(a, b, c) __builtin_amdgcn_mfma_f32_16x16x32_bf16((a), (b), (c), 0, 0, 0)

__device__ __forceinline__ u16 f2bf_rte(float f) {
  __hip_bfloat16 h = __float2bfloat16(f);
  u16 u;
  __builtin_memcpy(&u, &h, 2);
  return u;
}

__device__ __forceinline__ void gload16(const u16* g, u16* l) {
  __builtin_amdgcn_global_load_lds((const __attribute__((address_space(1))) u32*)g,
                                   (__attribute__((address_space(3))) u32*)l, 16, 0, 0);
}

// ---------------- f32 -> bf16 elementwise (q_s) ----------------
__global__ __launch_bounds__(256) void k_cvt(const float* __restrict__ in,
                                             u16* __restrict__ out, int n8) {
  int i = blockIdx.x * 256 + threadIdx.x;
  if (i >= n8) return;
  const f32x4* p = (const f32x4*)(in + (size_t)i * 8);
  f32x4 a = p[0], b = p[1];
  s16x8 o;
  for (int k = 0; k < 4; ++k) o[k] = (short)f2bf_rte(a[k]);
  for (int k = 0; k < 4; ++k) o[4 + k] = (short)f2bf_rte(b[k]);
  *(s16x8*)(out + (size_t)i * 8) = o;
}

// ---------------- transpose 4x 1024x1024 f32 weights -> bf16 (one launch) ----------------
__global__ __launch_bounds__(256) void k_transpose_w(const float* __restrict__ W0,
                                                     const float* __restrict__ W1,
                                                     const float* __restrict__ W2,
                                                     const float* __restrict__ W3,
                                                     u16* __restrict__ out) {
  const int z = blockIdx.z;
  const float* in = (z == 0) ? W0 : (z == 1) ? W1 : (z == 2) ? W2 : W3;
  u16* o = out + (size_t)z * 1024 * 1024;
  __shared__ u16 tile[64][65];
  const int t = threadIdx.x, tx = t & 63, ty = t >> 6;
  const int r0 = blockIdx.y * 64, c0 = blockIdx.x * 64;
  for (int rr = 0; rr < 16; ++rr) {
    int row = rr * 4 + ty;
    tile[row][tx] = f2bf_rte(in[(size_t)(r0 + row) * 1024 + c0 + tx]);
  }
  __syncthreads();
  for (int rr = 0; rr < 16; ++rr) {
    int row = rr * 4 + ty;
    o[(size_t)(c0 + row) * 1024 + r0 + tx] = tile[tx][row];
  }
}

// ---------------- transpose V [bh][2048][64] -> Vt[bh][64][2048] ----------------
__global__ __launch_bounds__(256) void k_transpose_v(const u16* __restrict__ V,
                                                     u16* __restrict__ Vt) {
  __shared__ u16 tile[64][65];
  const int t = threadIdx.x, tx = t & 63, ty = t >> 6;
  const int j0 = blockIdx.x * 64;
  const int bh = blockIdx.y;
  const u16* src = V + (size_t)bh * 2048 * 64;
  u16* dst = Vt + (size_t)bh * 64 * 2048;
  for (int rr = 0; rr < 16; ++rr) {
    int row = rr * 4 + ty;
    tile[row][tx] = src[(size_t)(j0 + row) * 64 + tx];
  }
  __syncthreads();
  for (int rr = 0; rr < 16; ++rr) {
    int d = rr * 4 + ty;
    dst[(size_t)d * 2048 + j0 + tx] = tile[tx][d];
  }
}

// ---------------- fused QKV GEMM: dbuf LDS + swizzled source (conflict-free) ----------------
// Q pre-scaled by 0.125*log2(e) (exp2-domain attention). K gets pos added.
__global__ __launch_bounds__(256) void k_qkv_gemm(const u16* __restrict__ X,
                                                  const u16* __restrict__ WT,
                                                  const float* __restrict__ pos,
                                                  u16* __restrict__ Qh,
                                                  u16* __restrict__ Kh,
                                                  u16* __restrict__ Vh) {
  __shared__ u16 As[2][4096];
  __shared__ u16 Bs[2][4096];
  const int t = threadIdx.x;
  const int lane = t & 63, wid = t >> 6;
  const int wr = wid >> 1, wc = wid & 1;
  const int g = lane >> 4, lr = lane & 15;
  const int m0 = blockIdx.y * 128, n0 = blockIdx.x * 128;

  const int srcRow = t >> 2;  // 0..63 (+64 for second gload)
  const int srcKsw = ((t & 3) * 8) ^ (((t >> 3) & 3) << 3);
  const u16* aSrc = &X[(size_t)(m0 + srcRow) * 1024 + srcKsw];
  const u16* bSrc = &WT[(size_t)(n0 + srcRow) * 1024 + srcKsw];

  const int csw = (g * 8) ^ (((lr >> 1) & 3) << 3);

  f32x4 acc[4][4] = {};

#define QKV_STAGE(buf, k0)                                   \
  {                                                          \
    gload16(aSrc + (k0), &As[buf][wid * 512]);               \
    gload16(aSrc + 65536 + (k0), &As[buf][wid * 512 + 2048]);\
    gload16(bSrc + (k0), &Bs[buf][wid * 512]);               \
    gload16(bSrc + 65536 + (k0), &Bs[buf][wid * 512 + 2048]);\
  }

  QKV_STAGE(0, 0);
  int cur = 0;
  for (int k0 = 0; k0 < 1024; k0 += 32) {
    __syncthreads();  // drains this tile's loads; prefetch below overlaps compute
    if (k0 < 992) QKV_STAGE(cur ^ 1, k0 + 32);
    s16x8 a[4], b[4];
#pragma unroll
    for (int mi = 0; mi < 4; ++mi)
      a[mi] = *(const s16x8*)&As[cur][(wr * 64 + mi * 16 + lr) * 32 + csw];
#pragma unroll
    for (int nj = 0; nj < 4; ++nj)
      b[nj] = *(const s16x8*)&Bs[cur][(wc * 64 + nj * 16 + lr) * 32 + csw];
#pragma unroll
    for (int mi = 0; mi < 4; ++mi)
#pragma unroll
      for (int nj = 0; nj < 4; ++nj)
        acc[mi][nj] = MFMA(a[mi], b[nj], acc[mi][nj]);
    cur ^= 1;
  }
#undef QKV_STAGE

  const float QSCALE = 0.125f * 1.44269504f;
  for (int mi = 0; mi < 4; ++mi) {
    for (int nj = 0; nj < 4; ++nj) {
      const int n_g = n0 + wc * 64 + nj * 16 + lr;
      const int buf = n_g >> 10;       // 0=Q 1=K 2=V
      const int col = n_g & 1023;
      const int h = col >> 6, d = col & 63;
      u16* dst = (buf == 0) ? Qh : ((buf == 1) ? Kh : Vh);
      for (int r = 0; r < 4; ++r) {
        const int row = m0 + wr * 64 + mi * 16 + g * 4 + r;  // 0..4095
        const int b = row >> 11, n = row & 2047;
        float v = acc[mi][nj][r];
        if (buf == 1) v += pos[(size_t)row * 1024 + col];
        if (buf == 0) v *= QSCALE;
        dst[(size_t)((b * 16 + h) * 2048 + n) * 64 + d] = f2bf_rte(v);
      }
    }
  }
}

// ---------------- flash attention: K+V dbuf LDS, 32 Q rows/wave, shared P buf ----------------
__global__ __launch_bounds__(256, 4) void k_attn(const u16* __restrict__ Qh,
                                                 const u16* __restrict__ Kh,
                                                 const u16* __restrict__ Vt,
                                                 u16* __restrict__ Oh) {
  const int t = threadIdx.x, lane = t & 63, wid = t >> 6;
  const int g = lane >> 4, lr = lane & 15;
  const int hid = blockIdx.x;
  const int lid = (hid & 7) * 64 + (hid >> 3);   // bijective XCD swizzle (512 % 8 == 0)
  const int bh = lid >> 4, itile = lid & 15;
  const int i0 = itile * 128 + wid * 16;         // wave rows: i0..i0+15 and i0+64..i0+79

  __shared__ char Ks[2][8192];     // K tile double buffer (swizzled)
  __shared__ char Vs[2][8192];     // V tile double buffer (swizzled)
  __shared__ char Ps[4][2048];     // per-wave P staging, time-shared by both row blocks

  char* Pw = Ps[wid];

  const u16* Qp = Qh + (size_t)bh * 2048 * 64;
  const u16* Kp = Kh + (size_t)bh * 2048 * 64;
  const u16* Vp = Vt + (size_t)bh * 64 * 2048;

  s16x8 aq0[2], aq1[2];
  aq0[0] = *(const s16x8*)&Qp[(size_t)(i0 + lr) * 64 + g * 8];
  aq0[1] = *(const s16x8*)&Qp[(size_t)(i0 + lr) * 64 + 32 + g * 8];
  aq1[0] = *(const s16x8*)&Qp[(size_t)(i0 + 64 + lr) * 64 + g * 8];
  aq1[1] = *(const s16x8*)&Qp[(size_t)(i0 + 64 + lr) * 64 + 32 + g * 8];

  f32x4 oa0[4] = {}, oa1[4] = {};
  float m0_[4], m1_[4], l0_[4], l1_[4];
  for (int r = 0; r < 4; ++r) {
    m0_[r] = -1e30f; m1_[r] = -1e30f; l0_[r] = 0.f; l1_[r] = 0.f;
  }

  // cooperative staging setup (256 threads stage 8KB K + 8KB V per tile)
  const int srow = t >> 3;          // 0..31
  const int sch = (t & 7) * 16;     // byte chunk
  const int swz = (srow & 7) << 4;  // (srow+32)&7 == srow&7
  const int sb0 = (srow * 128 + sch) ^ swz;
  const int sb1 = ((srow + 32) * 128 + sch) ^ swz;
  const u16* kB0 = &Kp[(size_t)srow * 64 + (sch >> 1)];
  const u16* kB1 = &Kp[(size_t)(srow + 32) * 64 + (sch >> 1)];
  const u16* vB0 = &Vp[(size_t)srow * 2048 + (sch >> 1)];
  const u16* vB1 = &Vp[(size_t)(srow + 32) * 2048 + (sch >> 1)];

  s16x8 kr0 = *(const s16x8*)kB0;
  s16x8 kr1 = *(const s16x8*)kB1;
  s16x8 vr0 = *(const s16x8*)vB0;
  s16x8 vr1 = *(const s16x8*)vB1;
  *(s16x8*)(Ks[0] + sb0) = kr0;
  *(s16x8*)(Ks[0] + sb1) = kr1;
  *(s16x8*)(Vs[0] + sb0) = vr0;
  *(s16x8*)(Vs[0] + sb1) = vr1;
  __syncthreads();

  for (int tt = 0; tt < 32; ++tt) {
    const int cur = tt & 1;
    // async-STAGE: issue next-tile global loads before compute (T14)
    if (tt < 31) {
      const size_t j1 = (size_t)(tt + 1) * 64;
      kr0 = *(const s16x8*)(kB0 + j1 * 64);
      kr1 = *(const s16x8*)(kB1 + j1 * 64);
      vr0 = *(const s16x8*)(vB0 + j1);
      vr1 = *(const s16x8*)(vB1 + j1);
    }
    const char* Kc = Ks[cur];
    const char* Vc = Vs[cur];

    // ---- QK^T from LDS: each K fragment feeds both row blocks ----
    f32x4 s0[4] = {}, s1[4] = {};
    __builtin_amdgcn_s_setprio(1);
#pragma unroll
    for (int jf = 0; jf < 4; ++jf) {
      const int row = jf * 16 + lr;
      const int bw = (row & 7) << 4;
      s16x8 bk0 = *(const s16x8*)(Kc + ((row * 128 + g * 16) ^ bw));
      s16x8 bk1 = *(const s16x8*)(Kc + ((row * 128 + 64 + g * 16) ^ bw));
      s0[jf] = MFMA(aq0[0], bk0, s0[jf]);
      s0[jf] = MFMA(aq0[1], bk1, s0[jf]);
      s1[jf] = MFMA(aq1[0], bk0, s1[jf]);
      s1[jf] = MFMA(aq1[1], bk1, s1[jf]);
    }
    __builtin_amdgcn_s_setprio(0);

    // ---- online softmax (defer-max + deferred l-reduction), both blocks ----
    {
      float tl[4];
      for (int r = 0; r < 4; ++r)
        tl[r] = fmaxf(fmaxf(s0[0][r], s0[1][r]), fmaxf(s0[2][r], s0[3][r]));
      int ok = (tl[0] <= m0_[0] + 8.f) & (tl[1] <= m0_[1] + 8.f) &
               (tl[2] <= m0_[2] + 8.f) & (tl[3] <= m0_[3] + 8.f);
      if (!__all(ok)) {
        for (int r = 0; r < 4; ++r) {
          float tm = tl[r];
          for (int m = 1; m < 16; m <<= 1) tm = fmaxf(tm, __shfl_xor(tm, m, 64));
          float mnew = fmaxf(m0_[r], tm);
          float alpha = __builtin_amdgcn_exp2f(m0_[r] - mnew);
          l0_[r] *= alpha;
          m0_[r] = mnew;
          for (int df = 0; df < 4; ++df) oa0[df][r] *= alpha;
        }
      }
#pragma unroll
      for (int jf = 0; jf < 4; ++jf)
        for (int r = 0; r < 4; ++r) {
          float p = __builtin_amdgcn_exp2f(s0[jf][r] - m0_[r]);
          s0[jf][r] = p;
          l0_[r] += p;
        }
    }
    {
      float tl[4];
      for (int r = 0; r < 4; ++r)
        tl[r] = fmaxf(fmaxf(s1[0][r], s1[1][r]), fmaxf(s1[2][r], s1[3][r]));
      int ok = (tl[0] <= m1_[0] + 8.f) & (tl[1] <= m1_[1] + 8.f) &
               (tl[2] <= m1_[2] + 8.f) & (tl[3] <= m1_[3] + 8.f);
      if (!__all(ok)) {
        for (int r = 0; r < 4; ++r) {
          float tm = tl[r];
          for (int m = 1; m < 16; m <<= 1) tm = fmaxf(tm, __shfl_xor(tm, m, 64));
          float mnew = fmaxf(m1_[r], tm);
          float alpha = __builtin_amdgcn_exp2f(m1_[r] - mnew);
          l1_[r] *= alpha;
          m1_[r] = mnew;
          for (int df = 0; df < 4; ++df) oa1[df][r] *= alpha;
        }
      }
#pragma unroll
      for (int jf = 0; jf < 4; ++jf)
        for (int r = 0; r < 4; ++r) {
          float p = __builtin_amdgcn_exp2f(s1[jf][r] - m1_[r]);
          s1[jf][r] = p;
          l1_[r] += p;
        }
    }

    // ---- P -> per-wave LDS, time-shared buffer: P0 write/read, then P1 ----
    const int bwp = (lr & 7) << 4;
    s16x8 pa0[2], pa1[2];
#pragma unroll
    for (int jf = 0; jf < 4; ++jf)
      for (int r = 0; r < 4; ++r) {
        const int row = g * 4 + r;
        const int off = (row * 128 + (jf * 16 + lr) * 2) ^ ((row & 7) << 4);
        *(u16*)(Pw + off) = f2bf_rte(s0[jf][r]);
      }
    pa0[0] = *(const s16x8*)(Pw + ((lr * 128 + g * 16) ^ bwp));
    pa0[1] = *(const s16x8*)(Pw + ((lr * 128 + 64 + g * 16) ^ bwp));
#pragma unroll
    for (int jf = 0; jf < 4; ++jf)
      for (int r = 0; r < 4; ++r) {
        const int row = g * 4 + r;
        const int off = (row * 128 + (jf * 16 + lr) * 2) ^ ((row & 7) << 4);
        *(u16*)(Pw + off) = f2bf_rte(s1[jf][r]);
      }
    pa1[0] = *(const s16x8*)(Pw + ((lr * 128 + g * 16) ^ bwp));
    pa1[1] = *(const s16x8*)(Pw + ((lr * 128 + 64 + g * 16) ^ bwp));

    // ---- PV from LDS: each V fragment feeds both row blocks ----
    __builtin_amdgcn_s_setprio(1);
#pragma unroll
    for (int df = 0; df < 4; ++df) {
      const int row = df * 16 + lr;
      const int bw = (row & 7) << 4;
      s16x8 bv0 = *(const s16x8*)(Vc + ((row * 128 + g * 16) ^ bw));
      s16x8 bv1 = *(const s16x8*)(Vc + ((row * 128 + 64 + g * 16) ^ bw));
      oa0[df] = MFMA(pa0[0], bv0, oa0[df]);
      oa0[df] = MFMA(pa0[1], bv1, oa0[df]);
      oa1[df] = MFMA(pa1[0], bv0, oa1[df]);
      oa1[df] = MFMA(pa1[1], bv1, oa1[df]);
    }
    __builtin_amdgcn_s_setprio(0);

    // ---- write next K/V tile into the other buffer, then sync ----
    if (tt < 31) {
      char* Kn = Ks[cur ^ 1];
      char* Vn = Vs[cur ^ 1];
      *(s16x8*)(Kn + sb0) = kr0;
      *(s16x8*)(Kn + sb1) = kr1;
      *(s16x8*)(Vn + sb0) = vr0;
      *(s16x8*)(Vn + sb1) = vr1;
    }
    __syncthreads();
  }

  // final cross-lane l reduction (16-lane butterfly within each group)
  for (int r = 0; r < 4; ++r) {
    float ps = l0_[r];
    for (int m = 1; m < 16; m <<= 1) ps += __shfl_xor(ps, m, 64);
    l0_[r] = ps;
    ps = l1_[r];
    for (int m = 1; m < 16; m <<= 1) ps += __shfl_xor(ps, m, 64);
    l1_[r] = ps;
  }

  u16* Op = Oh + (size_t)bh * 2048 * 64;
#pragma unroll
  for (int df = 0; df < 4; ++df)
    for (int r = 0; r < 4; ++r) {
      const int row0 = i0 + g * 4 + r;
      Op[(size_t)row0 * 64 + df * 16 + lr] = f2bf_rte(oa0[df][r] / l0_[r]);
      Op[(size_t)(row0 + 64) * 64 + df * 16 + lr] = f2bf_rte(oa1[df][r] / l1_[r]);
    }
}

// ---------------- out GEMM: dbuf LDS + swizzled source; + bo + q_s -> X (f32) ----------------
__global__ __launch_bounds__(256) void k_out_gemm(const u16* __restrict__ Oh,
                                                  const u16* __restrict__ WTo,
                                                  const float* __restrict__ bo,
                                                  const float* __restrict__ qs,
                                                  float* __restrict__ X) {
  __shared__ u16 As[2][4096];
  __shared__ u16 Bs[2][4096];
  const int t = threadIdx.x;
  const int lane = t & 63, wid = t >> 6;
  const int wr = wid >> 1, wc = wid & 1;
  const int g = lane >> 4, lr = lane & 15;
  const int m0 = blockIdx.y * 128, n0 = blockIdx.x * 128;

  const int srcRow = t >> 2;
  const int srcKsw = ((t & 3) * 8) ^ (((t >> 3) & 3) << 3);
  const int rg = m0 + srcRow, bb0 = rg >> 11, nn0 = rg & 2047;
  const int rg2 = rg + 64, bb2 = rg2 >> 11, nn2 = rg2 & 2047;
  const u16* bSrc = &WTo[(size_t)(n0 + srcRow) * 1024 + srcKsw];
  const int csw = (g * 8) ^ (((lr >> 1) & 3) << 3);

  f32x4 acc[4][4] = {};

#define OUT_STAGE(buf, k0)                                                        \
  {                                                                               \
    const int h_ = (k0) >> 6, d_ = ((k0) & 63) + srcKsw;                          \
    gload16(&Oh[((size_t)(bb0 * 16 + h_) * 2048 + nn0) * 64 + d_],                \
            &As[buf][wid * 512]);                                                 \
    gload16(&Oh[((size_t)(bb2 * 16 + h_) * 2048 + nn2) * 64 + d_],                \
            &As[buf][wid * 512 + 2048]);                                          \
    gload16(bSrc + (k0), &Bs[buf][wid * 512]);                                    \
    gload16(bSrc + 65536 + (k0), &Bs[buf][wid * 512 + 2048]);                     \
  }

  OUT_STAGE(0, 0);
  int cur = 0;
  for (int k0 = 0; k0 < 1024; k0 += 32) {
    __syncthreads();
    if (k0 < 992) OUT_STAGE(cur ^ 1, k0 + 32);
    s16x8 a[4], b[4];
#pragma unroll
    for (int mi = 0; mi < 4; ++mi)
      a[mi] = *(const s16x8*)&As[cur][(wr * 64 + mi * 16 + lr) * 32 + csw];
#pragma unroll
    for (int nj = 0; nj < 4; ++nj)
      b[nj] = *(const s16x8*)&Bs[cur][(wc * 64 + nj * 16 + lr) * 32 + csw];
#pragma unroll
    for (int mi = 0; mi < 4; ++mi)
#pragma unroll
      for (int nj = 0; nj < 4; ++nj)
        acc[mi][nj] = MFMA(a[mi], b[nj], acc[mi][nj]);
    cur ^= 1;
  }
#undef OUT_STAGE

  for (int mi = 0; mi < 4; ++mi) {
    for (int nj = 0; nj < 4; ++nj) {
      const int col = n0 + wc * 64 + nj * 16 + lr;
      for (int r = 0; r < 4; ++r) {
        const int row = m0 + wr * 64 + mi * 16 + g * 4 + r;
        float v = acc[mi][nj][r] + bo[col] + qs[(size_t)row * 1024 + col];
        X[(size_t)row * 1024 + col] = v;
      }
    }
  }
}

// ---------------- LayerNorm rows of 1024 (f32 in, f32 out) ----------------
__global__ __launch_bounds__(256) void k_ln(const float* __restrict__ X,
                                            const float* __restrict__ gg,
                                            const float* __restrict__ bb,
                                            float* __restrict__ out) {
  const int row = blockIdx.x, t = threadIdx.x;
  const int wid = t >> 6, lane = t & 63;
  const float* xr = X + (size_t)row * 1024;
  f32x4 x = *(const f32x4*)&xr[t * 4];
  float s1 = x[0] + x[1] + x[2] + x[3];
  float s2 = x[0] * x[0] + x[1] * x[1] + x[2] * x[2] + x[3] * x[3];
  for (int off = 32; off > 0; off >>= 1) {
    s1 += __shfl_down(s1, off, 64);
    s2 += __shfl_down(s2, off, 64);
  }
  __shared__ float red[2][4];
  if (lane == 0) { red[0][wid] = s1; red[1][wid] = s2; }
  __syncthreads();
  s1 = red[0][0] + red[0][1] + red[0][2] + red[0][3];
  s2 = red[1][0] + red[1][1] + red[1][2] + red[1][3];
  const float mu = s1 * (1.f / 1024.f);
  const float var = s2 * (1.f / 1024.f) - mu * mu;
  const float rstd = rsqrtf(var + 1e-5f);
  f32x4 gv = *(const f32x4*)&gg[t * 4];
  f32x4 bv = *(const f32x4*)&bb[t * 4];
  f32x4 ov;
  for (int i = 0; i < 4; ++i) ov[i] = (x[i] - mu) * rstd * gv[i] + bv[i];
  *(f32x4*)&out[(size_t)row * 1024 + t * 4] = ov;
}

extern "C" void kernel_launch(void* const* d_in, const int* in_sizes, int n_in,
                              void* d_out, int out_size, void* d_ws, size_t ws_size,
                              hipStream_t stream) {
  (void)in_sizes; (void)n_in; (void)out_size; (void)ws_size;
  const float* q_s = (const float*)d_in[0];
  const float* pos = (const float*)d_in[1];
  const float* Wq = (const float*)d_in[2];
  const float* Wk = (const float*)d_in[3];
  const float* Wv = (const float*)d_in[4];
  const float* Wo = (const float*)d_in[5];
  const float* bo = (const float*)d_in[6];
  const float* lng = (const float*)d_in[7];
  const float* lnb = (const float*)d_in[8];
  float* out = (float*)d_out;

  u16* ws = (u16*)d_ws;
  const size_t MB1 = 1024 * 1024;  // elements
  u16* WT  = ws;                   // 4 x 1M bf16 (Wq^T,Wk^T,Wv^T,Wo^T)
  u16* Xbf = ws + 4 * MB1;         // q_s as bf16
  u16* Qh  = Xbf + 4 * MB1;        // [32][2048][64]
  u16* Kh  = Qh + 4 * MB1;
  u16* Vh  = Kh + 4 * MB1;
  u16* Vt  = Vh + 4 * MB1;         // [32][64][2048]
  u16* Oh  = Vt + 4 * MB1;         // [32][2048][64]
  float* Xb = (float*)Qh;          // f32 pre-LN x, aliases Qh+Kh (dead after attn)

  dim3 blk(256);
  k_cvt<<<dim3(2048), blk, 0, stream>>>(q_s, Xbf, 4 * MB1 / 8);
  k_transpose_w<<<dim3(16, 16, 4), blk, 0, stream>>>(Wq, Wk, Wv, Wo, WT);
  k_qkv_gemm<<<dim3(24, 32), blk, 0, stream>>>(Xbf, WT, pos, Qh, Kh, Vh);
  k_transpose_v<<<dim3(32, 32), blk, 0, stream>>>(Vh, Vt);
  k_attn<<<dim3(512), blk, 0, stream>>>(Qh, Kh, Vt, Oh);
  k_out_gemm<<<dim3(8, 32), blk, 0, stream>>>(Oh, WT + 3 * MB1, bo, q_s, Xb);
  k_ln<<<4096, blk, 0, stream>>>(Xb, lng, lnb, out);
}

// Round 10
// 158.134 us; speedup vs baseline: 1.2741x; 1.2741x over previous
//
#include <hip/hip_runtime.h>
#include <hip/hip_bf16.h>
#include <stdint.h>

typedef unsigned short u16;
typedef unsigned int u32;
typedef short s16x8 __attribute__((ext_vector_type(8)));
typedef short s16x4 __attribute__((ext_vector_type(4)));
typedef float f32x4 __attribute__((ext_vector_type(4)));

#define MFMA(a, b, c) __builtin_amdgcn_mfma_f32_16x16x32_bf16((a), (b), (c), 0, 0, 0)

__device__ __forceinline__ u16 f2bf_rte(float f) {
  __hip_bfloat16 h = __float2bfloat16(f);
  u16 u;
  __builtin_memcpy(&u, &h, 2);
  return u;
}

__device__ __forceinline__ void gload16(const u16* g, u16* l) {
  __builtin_amdgcn_global_load_lds((const __attribute__((address_space(1))) u32*)g,
                                   (__attribute__((address_space(3))) u32*)l, 16, 0, 0);
}

// ---------------- f32 -> bf16 elementwise (q_s) ----------------
__global__ __launch_bounds__(256) void k_cvt(const float* __restrict__ in,
                                             u16* __restrict__ out, int n8) {
  int i = blockIdx.x * 256 + threadIdx.x;
  if (i >= n8) return;
  const f32x4* p = (const f32x4*)(in + (size_t)i * 8);
  f32x4 a = p[0], b = p[1];
  s16x8 o;
  for (int k = 0; k < 4; ++k) o[k] = (short)f2bf_rte(a[k]);
  for (int k = 0; k < 4; ++k) o[4 + k] = (short)f2bf_rte(b[k]);
  *(s16x8*)(out + (size_t)i * 8) = o;
}

// ---------------- transpose 4x 1024x1024 f32 weights -> bf16 (one launch) ----------------
__global__ __launch_bounds__(256) void k_transpose_w(const float* __restrict__ W0,
                                                     const float* __restrict__ W1,
                                                     const float* __restrict__ W2,
                                                     const float* __restrict__ W3,
                                                     u16* __restrict__ out) {
  const int z = blockIdx.z;
  const float* in = (z == 0) ? W0 : (z == 1) ? W1 : (z == 2) ? W2 : W3;
  u16* o = out + (size_t)z * 1024 * 1024;
  __shared__ u16 tile[64][65];
  const int t = threadIdx.x, tx = t & 63, ty = t >> 6;
  const int r0 = blockIdx.y * 64, c0 = blockIdx.x * 64;
  for (int rr = 0; rr < 16; ++rr) {
    int row = rr * 4 + ty;
    tile[row][tx] = f2bf_rte(in[(size_t)(r0 + row) * 1024 + c0 + tx]);
  }
  __syncthreads();
  for (int rr = 0; rr < 16; ++rr) {
    int row = rr * 4 + ty;
    o[(size_t)(c0 + row) * 1024 + r0 + tx] = tile[tx][row];
  }
}

// ---------------- transpose V [bh][2048][64] -> Vt[bh][64][2048] ----------------
__global__ __launch_bounds__(256) void k_transpose_v(const u16* __restrict__ V,
                                                     u16* __restrict__ Vt) {
  __shared__ u16 tile[64][65];
  const int t = threadIdx.x, tx = t & 63, ty = t >> 6;
  const int j0 = blockIdx.x * 64;
  const int bh = blockIdx.y;
  const u16* src = V + (size_t)bh * 2048 * 64;
  u16* dst = Vt + (size_t)bh * 64 * 2048;
  for (int rr = 0; rr < 16; ++rr) {
    int row = rr * 4 + ty;
    tile[row][tx] = src[(size_t)(j0 + row) * 64 + tx];
  }
  __syncthreads();
  for (int rr = 0; rr < 16; ++rr) {
    int d = rr * 4 + ty;
    dst[(size_t)d * 2048 + j0 + tx] = tile[tx][d];
  }
}

// ---------------- fused QKV GEMM: dbuf LDS + swizzled source + XCD swizzle ----------------
// Q pre-scaled by 0.125*log2(e) (exp2-domain attention). K gets pos added.
__global__ __launch_bounds__(256) void k_qkv_gemm(const u16* __restrict__ X,
                                                  const u16* __restrict__ WT,
                                                  const float* __restrict__ pos,
                                                  u16* __restrict__ Qh,
                                                  u16* __restrict__ Kh,
                                                  u16* __restrict__ Vh) {
  __shared__ u16 As[2][4096];
  __shared__ u16 Bs[2][4096];
  const int t = threadIdx.x;
  const int lane = t & 63, wid = t >> 6;
  const int wr = wid >> 1, wc = wid & 1;
  const int g = lane >> 4, lr = lane & 15;
  // bijective XCD swizzle over 768 blocks (768 % 8 == 0): each XCD owns
  // contiguous runs of 4 m-panels x 24 n-tiles -> A-panel L2 locality.
  const int lin = blockIdx.y * 24 + blockIdx.x;
  const int swz = (lin & 7) * 96 + (lin >> 3);
  const int m0 = (swz / 24) * 128, n0 = (swz % 24) * 128;

  const int srcRow = t >> 2;  // 0..63 (+64 for second gload)
  const int srcKsw = ((t & 3) * 8) ^ (((t >> 3) & 3) << 3);
  const u16* aSrc = &X[(size_t)(m0 + srcRow) * 1024 + srcKsw];
  const u16* bSrc = &WT[(size_t)(n0 + srcRow) * 1024 + srcKsw];

  const int csw = (g * 8) ^ (((lr >> 1) & 3) << 3);

  f32x4 acc[4][4] = {};

#define QKV_STAGE(buf, k0)                                   \
  {                                                          \
    gload16(aSrc + (k0), &As[buf][wid * 512]);               \
    gload16(aSrc + 65536 + (k0), &As[buf][wid * 512 + 2048]);\
    gload16(bSrc + (k0), &Bs[buf][wid * 512]);               \
    gload16(bSrc + 65536 + (k0), &Bs[buf][wid * 512 + 2048]);\
  }

  QKV_STAGE(0, 0);
  int cur = 0;
  for (int k0 = 0; k0 < 1024; k0 += 32) {
    __syncthreads();  // drains this tile's loads; prefetch below overlaps compute
    if (k0 < 992) QKV_STAGE(cur ^ 1, k0 + 32);
    s16x8 a[4], b[4];
#pragma unroll
    for (int mi = 0; mi < 4; ++mi)
      a[mi] = *(const s16x8*)&As[cur][(wr * 64 + mi * 16 + lr) * 32 + csw];
#pragma unroll
    for (int nj = 0; nj < 4; ++nj)
      b[nj] = *(const s16x8*)&Bs[cur][(wc * 64 + nj * 16 + lr) * 32 + csw];
#pragma unroll
    for (int mi = 0; mi < 4; ++mi)
#pragma unroll
      for (int nj = 0; nj < 4; ++nj)
        acc[mi][nj] = MFMA(a[mi], b[nj], acc[mi][nj]);
    cur ^= 1;
  }
#undef QKV_STAGE

  const float QSCALE = 0.125f * 1.44269504f;
  for (int mi = 0; mi < 4; ++mi) {
    for (int nj = 0; nj < 4; ++nj) {
      const int n_g = n0 + wc * 64 + nj * 16 + lr;
      const int buf = n_g >> 10;       // 0=Q 1=K 2=V
      const int col = n_g & 1023;
      const int h = col >> 6, d = col & 63;
      u16* dst = (buf == 0) ? Qh : ((buf == 1) ? Kh : Vh);
      for (int r = 0; r < 4; ++r) {
        const int row = m0 + wr * 64 + mi * 16 + g * 4 + r;  // 0..4095
        const int b = row >> 11, n = row & 2047;
        float v = acc[mi][nj][r];
        if (buf == 1) v += pos[(size_t)row * 1024 + col];
        if (buf == 0) v *= QSCALE;
        dst[(size_t)((b * 16 + h) * 2048 + n) * 64 + d] = f2bf_rte(v);
      }
    }
  }
}

// ---------------- flash attention: K+V dbuf LDS, 32 Q rows/wave (round-8 version) ----------------
__global__ __launch_bounds__(256, 2) void k_attn(const u16* __restrict__ Qh,
                                                 const u16* __restrict__ Kh,
                                                 const u16* __restrict__ Vt,
                                                 u16* __restrict__ Oh) {
  const int t = threadIdx.x, lane = t & 63, wid = t >> 6;
  const int g = lane >> 4, lr = lane & 15;
  const int hid = blockIdx.x;
  const int lid = (hid & 7) * 64 + (hid >> 3);   // bijective XCD swizzle (512 % 8 == 0)
  const int bh = lid >> 4, itile = lid & 15;
  const int i0 = itile * 128 + wid * 16;         // wave rows: i0..i0+15 and i0+64..i0+79

  __shared__ char Ks[2][8192];     // K tile double buffer (swizzled)
  __shared__ char Vs[2][8192];     // V tile double buffer (swizzled)
  __shared__ char Ps[4][2][2048];  // per-wave, per-row-block P staging

  char* Pw0 = Ps[wid][0];
  char* Pw1 = Ps[wid][1];

  const u16* Qp = Qh + (size_t)bh * 2048 * 64;
  const u16* Kp = Kh + (size_t)bh * 2048 * 64;
  const u16* Vp = Vt + (size_t)bh * 64 * 2048;

  s16x8 aq0[2], aq1[2];
  aq0[0] = *(const s16x8*)&Qp[(size_t)(i0 + lr) * 64 + g * 8];
  aq0[1] = *(const s16x8*)&Qp[(size_t)(i0 + lr) * 64 + 32 + g * 8];
  aq1[0] = *(const s16x8*)&Qp[(size_t)(i0 + 64 + lr) * 64 + g * 8];
  aq1[1] = *(const s16x8*)&Qp[(size_t)(i0 + 64 + lr) * 64 + 32 + g * 8];

  f32x4 oa0[4] = {}, oa1[4] = {};
  float m0_[4], m1_[4], l0_[4], l1_[4];
  for (int r = 0; r < 4; ++r) {
    m0_[r] = -1e30f; m1_[r] = -1e30f; l0_[r] = 0.f; l1_[r] = 0.f;
  }

  // cooperative staging setup (256 threads stage 8KB K + 8KB V per tile)
  const int srow = t >> 3;          // 0..31
  const int sch = (t & 7) * 16;     // byte chunk
  const int swz = (srow & 7) << 4;  // (srow+32)&7 == srow&7
  const int sb0 = (srow * 128 + sch) ^ swz;
  const int sb1 = ((srow + 32) * 128 + sch) ^ swz;
  const u16* kB0 = &Kp[(size_t)srow * 64 + (sch >> 1)];
  const u16* kB1 = &Kp[(size_t)(srow + 32) * 64 + (sch >> 1)];
  const u16* vB0 = &Vp[(size_t)srow * 2048 + (sch >> 1)];
  const u16* vB1 = &Vp[(size_t)(srow + 32) * 2048 + (sch >> 1)];

  s16x8 kr0 = *(const s16x8*)kB0;
  s16x8 kr1 = *(const s16x8*)kB1;
  s16x8 vr0 = *(const s16x8*)vB0;
  s16x8 vr1 = *(const s16x8*)vB1;
  *(s16x8*)(Ks[0] + sb0) = kr0;
  *(s16x8*)(Ks[0] + sb1) = kr1;
  *(s16x8*)(Vs[0] + sb0) = vr0;
  *(s16x8*)(Vs[0] + sb1) = vr1;
  __syncthreads();

  for (int tt = 0; tt < 32; ++tt) {
    const int cur = tt & 1;
    // async-STAGE: issue next-tile global loads before compute (T14)
    if (tt < 31) {
      const size_t j1 = (size_t)(tt + 1) * 64;
      kr0 = *(const s16x8*)(kB0 + j1 * 64);
      kr1 = *(const s16x8*)(kB1 + j1 * 64);
      vr0 = *(const s16x8*)(vB0 + j1);
      vr1 = *(const s16x8*)(vB1 + j1);
    }
    const char* Kc = Ks[cur];
    const char* Vc = Vs[cur];

    // ---- QK^T from LDS: each K fragment feeds both row blocks ----
    f32x4 s0[4] = {}, s1[4] = {};
    __builtin_amdgcn_s_setprio(1);
#pragma unroll
    for (int jf = 0; jf < 4; ++jf) {
      const int row = jf * 16 + lr;
      const int bw = (row & 7) << 4;
      s16x8 bk0 = *(const s16x8*)(Kc + ((row * 128 + g * 16) ^ bw));
      s16x8 bk1 = *(const s16x8*)(Kc + ((row * 128 + 64 + g * 16) ^ bw));
      s0[jf] = MFMA(aq0[0], bk0, s0[jf]);
      s0[jf] = MFMA(aq0[1], bk1, s0[jf]);
      s1[jf] = MFMA(aq1[0], bk0, s1[jf]);
      s1[jf] = MFMA(aq1[1], bk1, s1[jf]);
    }
    __builtin_amdgcn_s_setprio(0);

    // ---- online softmax (defer-max + deferred l-reduction), both blocks ----
    {
      float tl[4];
      for (int r = 0; r < 4; ++r)
        tl[r] = fmaxf(fmaxf(s0[0][r], s0[1][r]), fmaxf(s0[2][r], s0[3][r]));
      int ok = (tl[0] <= m0_[0] + 8.f) & (tl[1] <= m0_[1] + 8.f) &
               (tl[2] <= m0_[2] + 8.f) & (tl[3] <= m0_[3] + 8.f);
      if (!__all(ok)) {
        for (int r = 0; r < 4; ++r) {
          float tm = tl[r];
          for (int m = 1; m < 16; m <<= 1) tm = fmaxf(tm, __shfl_xor(tm, m, 64));
          float mnew = fmaxf(m0_[r], tm);
          float alpha = __builtin_amdgcn_exp2f(m0_[r] - mnew);
          l0_[r] *= alpha;
          m0_[r] = mnew;
          for (int df = 0; df < 4; ++df) oa0[df][r] *= alpha;
        }
      }
#pragma unroll
      for (int jf = 0; jf < 4; ++jf)
        for (int r = 0; r < 4; ++r) {
          float p = __builtin_amdgcn_exp2f(s0[jf][r] - m0_[r]);
          s0[jf][r] = p;
          l0_[r] += p;
        }
    }
    {
      float tl[4];
      for (int r = 0; r < 4; ++r)
        tl[r] = fmaxf(fmaxf(s1[0][r], s1[1][r]), fmaxf(s1[2][r], s1[3][r]));
      int ok = (tl[0] <= m1_[0] + 8.f) & (tl[1] <= m1_[1] + 8.f) &
               (tl[2] <= m1_[2] + 8.f) & (tl[3] <= m1_[3] + 8.f);
      if (!__all(ok)) {
        for (int r = 0; r < 4; ++r) {
          float tm = tl[r];
          for (int m = 1; m < 16; m <<= 1) tm = fmaxf(tm, __shfl_xor(tm, m, 64));
          float mnew = fmaxf(m1_[r], tm);
          float alpha = __builtin_amdgcn_exp2f(m1_[r] - mnew);
          l1_[r] *= alpha;
          m1_[r] = mnew;
          for (int df = 0; df < 4; ++df) oa1[df][r] *= alpha;
        }
      }
#pragma unroll
      for (int jf = 0; jf < 4; ++jf)
        for (int r = 0; r < 4; ++r) {
          float p = __builtin_amdgcn_exp2f(s1[jf][r] - m1_[r]);
          s1[jf][r] = p;
          l1_[r] += p;
        }
    }

    // ---- P -> per-wave LDS (two independent buffers; intra-wave ordering) ----
#pragma unroll
    for (int jf = 0; jf < 4; ++jf)
      for (int r = 0; r < 4; ++r) {
        const int row = g * 4 + r;
        const int off = (row * 128 + (jf * 16 + lr) * 2) ^ ((row & 7) << 4);
        *(u16*)(Pw0 + off) = f2bf_rte(s0[jf][r]);
        *(u16*)(Pw1 + off) = f2bf_rte(s1[jf][r]);
      }

    s16x8 pa0[2], pa1[2];
    {
      const int bw = (lr & 7) << 4;
      pa0[0] = *(const s16x8*)(Pw0 + ((lr * 128 + g * 16) ^ bw));
      pa0[1] = *(const s16x8*)(Pw0 + ((lr * 128 + 64 + g * 16) ^ bw));
      pa1[0] = *(const s16x8*)(Pw1 + ((lr * 128 + g * 16) ^ bw));
      pa1[1] = *(const s16x8*)(Pw1 + ((lr * 128 + 64 + g * 16) ^ bw));
    }

    // ---- PV from LDS: each V fragment feeds both row blocks ----
    __builtin_amdgcn_s_setprio(1);
#pragma unroll
    for (int df = 0; df < 4; ++df) {
      const int row = df * 16 + lr;
      const int bw = (row & 7) << 4;
      s16x8 bv0 = *(const s16x8*)(Vc + ((row * 128 + g * 16) ^ bw));
      s16x8 bv1 = *(const s16x8*)(Vc + ((row * 128 + 64 + g * 16) ^ bw));
      oa0[df] = MFMA(pa0[0], bv0, oa0[df]);
      oa0[df] = MFMA(pa0[1], bv1, oa0[df]);
      oa1[df] = MFMA(pa1[0], bv0, oa1[df]);
      oa1[df] = MFMA(pa1[1], bv1, oa1[df]);
    }
    __builtin_amdgcn_s_setprio(0);

    // ---- write next K/V tile into the other buffer, then sync ----
    if (tt < 31) {
      char* Kn = Ks[cur ^ 1];
      char* Vn = Vs[cur ^ 1];
      *(s16x8*)(Kn + sb0) = kr0;
      *(s16x8*)(Kn + sb1) = kr1;
      *(s16x8*)(Vn + sb0) = vr0;
      *(s16x8*)(Vn + sb1) = vr1;
    }
    __syncthreads();
  }

  // final cross-lane l reduction (16-lane butterfly within each group)
  for (int r = 0; r < 4; ++r) {
    float ps = l0_[r];
    for (int m = 1; m < 16; m <<= 1) ps += __shfl_xor(ps, m, 64);
    l0_[r] = ps;
    ps = l1_[r];
    for (int m = 1; m < 16; m <<= 1) ps += __shfl_xor(ps, m, 64);
    l1_[r] = ps;
  }

  u16* Op = Oh + (size_t)bh * 2048 * 64;
#pragma unroll
  for (int df = 0; df < 4; ++df)
    for (int r = 0; r < 4; ++r) {
      const int row0 = i0 + g * 4 + r;
      Op[(size_t)row0 * 64 + df * 16 + lr] = f2bf_rte(oa0[df][r] / l0_[r]);
      Op[(size_t)(row0 + 64) * 64 + df * 16 + lr] = f2bf_rte(oa1[df][r] / l1_[r]);
    }
}

// ---------------- out GEMM: dbuf LDS + swizzled source + XCD swizzle ----------------
__global__ __launch_bounds__(256) void k_out_gemm(const u16* __restrict__ Oh,
                                                  const u16* __restrict__ WTo,
                                                  const float* __restrict__ bo,
                                                  const float* __restrict__ qs,
                                                  float* __restrict__ X) {
  __shared__ u16 As[2][4096];
  __shared__ u16 Bs[2][4096];
  const int t = threadIdx.x;
  const int lane = t & 63, wid = t >> 6;
  const int wr = wid >> 1, wc = wid & 1;
  const int g = lane >> 4, lr = lane & 15;
  // bijective XCD swizzle over 256 blocks (256 % 8 == 0)
  const int lin = blockIdx.y * 8 + blockIdx.x;
  const int swz = (lin & 7) * 32 + (lin >> 3);
  const int m0 = (swz / 8) * 128, n0 = (swz % 8) * 128;

  const int srcRow = t >> 2;
  const int srcKsw = ((t & 3) * 8) ^ (((t >> 3) & 3) << 3);
  const int rg = m0 + srcRow, bb0 = rg >> 11, nn0 = rg & 2047;
  const int rg2 = rg + 64, bb2 = rg2 >> 11, nn2 = rg2 & 2047;
  const u16* bSrc = &WTo[(size_t)(n0 + srcRow) * 1024 + srcKsw];
  const int csw = (g * 8) ^ (((lr >> 1) & 3) << 3);

  f32x4 acc[4][4] = {};

#define OUT_STAGE(buf, k0)                                                        \
  {                                                                               \
    const int h_ = (k0) >> 6, d_ = ((k0) & 63) + srcKsw;                          \
    gload16(&Oh[((size_t)(bb0 * 16 + h_) * 2048 + nn0) * 64 + d_],                \
            &As[buf][wid * 512]);                                                 \
    gload16(&Oh[((size_t)(bb2 * 16 + h_) * 2048 + nn2) * 64 + d_],                \
            &As[buf][wid * 512 + 2048]);                                          \
    gload16(bSrc + (k0), &Bs[buf][wid * 512]);                                    \
    gload16(bSrc + 65536 + (k0), &Bs[buf][wid * 512 + 2048]);                     \
  }

  OUT_STAGE(0, 0);
  int cur = 0;
  for (int k0 = 0; k0 < 1024; k0 += 32) {
    __syncthreads();
    if (k0 < 992) OUT_STAGE(cur ^ 1, k0 + 32);
    s16x8 a[4], b[4];
#pragma unroll
    for (int mi = 0; mi < 4; ++mi)
      a[mi] = *(const s16x8*)&As[cur][(wr * 64 + mi * 16 + lr) * 32 + csw];
#pragma unroll
    for (int nj = 0; nj < 4; ++nj)
      b[nj] = *(const s16x8*)&Bs[cur][(wc * 64 + nj * 16 + lr) * 32 + csw];
#pragma unroll
    for (int mi = 0; mi < 4; ++mi)
#pragma unroll
      for (int nj = 0; nj < 4; ++nj)
        acc[mi][nj] = MFMA(a[mi], b[nj], acc[mi][nj]);
    cur ^= 1;
  }
#undef OUT_STAGE

  for (int mi = 0; mi < 4; ++mi) {
    for (int nj = 0; nj < 4; ++nj) {
      const int col = n0 + wc * 64 + nj * 16 + lr;
      for (int r = 0; r < 4; ++r) {
        const int row = m0 + wr * 64 + mi * 16 + g * 4 + r;
        float v = acc[mi][nj][r] + bo[col] + qs[(size_t)row * 1024 + col];
        X[(size_t)row * 1024 + col] = v;
      }
    }
  }
}

// ---------------- LayerNorm rows of 1024 (f32 in, f32 out) ----------------
__global__ __launch_bounds__(256) void k_ln(const float* __restrict__ X,
                                            const float* __restrict__ gg,
                                            const float* __restrict__ bb,
                                            float* __restrict__ out) {
  const int row = blockIdx.x, t = threadIdx.x;
  const int wid = t >> 6, lane = t & 63;
  const float* xr = X + (size_t)row * 1024;
  f32x4 x = *(const f32x4*)&xr[t * 4];
  float s1 = x[0] + x[1] + x[2] + x[3];
  float s2 = x[0] * x[0] + x[1] * x[1] + x[2] * x[2] + x[3] * x[3];
  for (int off = 32; off > 0; off >>= 1) {
    s1 += __shfl_down(s1, off, 64);
    s2 += __shfl_down(s2, off, 64);
  }
  __shared__ float red[2][4];
  if (lane == 0) { red[0][wid] = s1; red[1][wid] = s2; }
  __syncthreads();
  s1 = red[0][0] + red[0][1] + red[0][2] + red[0][3];
  s2 = red[1][0] + red[1][1] + red[1][2] + red[1][3];
  const float mu = s1 * (1.f / 1024.f);
  const float var = s2 * (1.f / 1024.f) - mu * mu;
  const float rstd = rsqrtf(var + 1e-5f);
  f32x4 gv = *(const f32x4*)&gg[t * 4];
  f32x4 bv = *(const f32x4*)&bb[t * 4];
  f32x4 ov;
  for (int i = 0; i < 4; ++i) ov[i] = (x[i] - mu) * rstd * gv[i] + bv[i];
  *(f32x4*)&out[(size_t)row * 1024 + t * 4] = ov;
}

extern "C" void kernel_launch(void* const* d_in, const int* in_sizes, int n_in,
                              void* d_out, int out_size, void* d_ws, size_t ws_size,
                              hipStream_t stream) {
  (void)in_sizes; (void)n_in; (void)out_size; (void)ws_size;
  const float* q_s = (const float*)d_in[0];
  const float* pos = (const float*)d_in[1];
  const float* Wq = (const float*)d_in[2];
  const float* Wk = (const float*)d_in[3];
  const float* Wv = (const float*)d_in[4];
  const float* Wo = (const float*)d_in[5];
  const float* bo = (const float*)d_in[6];
  const float* lng = (const float*)d_in[7];
  const float* lnb = (const float*)d_in[8];
  float* out = (float*)d_out;

  u16* ws = (u16*)d_ws;
  const size_t MB1 = 1024 * 1024;  // elements
  u16* WT  = ws;                   // 4 x 1M bf16 (Wq^T,Wk^T,Wv^T,Wo^T)
  u16* Xbf = ws + 4 * MB1;         // q_s as bf16
  u16* Qh  = Xbf + 4 * MB1;        // [32][2048][64]
  u16* Kh  = Qh + 4 * MB1;
  u16* Vh  = Kh + 4 * MB1;
  u16* Vt  = Vh + 4 * MB1;         // [32][64][2048]
  u16* Oh  = Vt + 4 * MB1;         // [32][2048][64]
  float* Xb = (float*)Qh;          // f32 pre-LN x, aliases Qh+Kh (dead after attn)

  dim3 blk(256);
  k_cvt<<<dim3(2048), blk, 0, stream>>>(q_s, Xbf, 4 * MB1 / 8);
  k_transpose_w<<<dim3(16, 16, 4), blk, 0, stream>>>(Wq, Wk, Wv, Wo, WT);
  k_qkv_gemm<<<dim3(24, 32), blk, 0, stream>>>(Xbf, WT, pos, Qh, Kh, Vh);
  k_transpose_v<<<dim3(32, 32), blk, 0, stream>>>(Vh, Vt);
  k_attn<<<dim3(512), blk, 0, stream>>>(Qh, Kh, Vt, Oh);
  k_out_gemm<<<dim3(8, 32), blk, 0, stream>>>(Oh, WT + 3 * MB1, bo, q_s, Xb);
  k_ln<<<4096, blk, 0, stream>>>(Xb, lng, lnb, out);
}

// Round 11
// 155.431 us; speedup vs baseline: 1.2963x; 1.0174x over previous
//
#include <hip/hip_runtime.h>
#include <hip/hip_bf16.h>
#include <stdint.h>

typedef unsigned short u16;
typedef unsigned int u32;
typedef short s16x8 __attribute__((ext_vector_type(8)));
typedef short s16x4 __attribute__((ext_vector_type(4)));
typedef float f32x4 __attribute__((ext_vector_type(4)));

#define MFMA(a, b, c) __builtin_amdgcn_mfma_f32_16x16x32_bf16((a), (b), (c), 0, 0, 0)

__device__ __forceinline__ u16 f2bf_rte(float f) {
  __hip_bfloat16 h = __float2bfloat16(f);
  u16 u;
  __builtin_memcpy(&u, &h, 2);
  return u;
}

__device__ __forceinline__ void gload16(const u16* g, u16* l) {
  __builtin_amdgcn_global_load_lds((const __attribute__((address_space(1))) u32*)g,
                                   (__attribute__((address_space(3))) u32*)l, 16, 0, 0);
}

// ---------------- f32 -> bf16 elementwise (q_s) ----------------
__global__ __launch_bounds__(256) void k_cvt(const float* __restrict__ in,
                                             u16* __restrict__ out, int n8) {
  int i = blockIdx.x * 256 + threadIdx.x;
  if (i >= n8) return;
  const f32x4* p = (const f32x4*)(in + (size_t)i * 8);
  f32x4 a = p[0], b = p[1];
  s16x8 o;
  for (int k = 0; k < 4; ++k) o[k] = (short)f2bf_rte(a[k]);
  for (int k = 0; k < 4; ++k) o[4 + k] = (short)f2bf_rte(b[k]);
  *(s16x8*)(out + (size_t)i * 8) = o;
}

// ---------------- transpose 4x 1024x1024 f32 weights -> bf16 (one launch) ----------------
__global__ __launch_bounds__(256) void k_transpose_w(const float* __restrict__ W0,
                                                     const float* __restrict__ W1,
                                                     const float* __restrict__ W2,
                                                     const float* __restrict__ W3,
                                                     u16* __restrict__ out) {
  const int z = blockIdx.z;
  const float* in = (z == 0) ? W0 : (z == 1) ? W1 : (z == 2) ? W2 : W3;
  u16* o = out + (size_t)z * 1024 * 1024;
  __shared__ u16 tile[64][65];
  const int t = threadIdx.x, tx = t & 63, ty = t >> 6;
  const int r0 = blockIdx.y * 64, c0 = blockIdx.x * 64;
  for (int rr = 0; rr < 16; ++rr) {
    int row = rr * 4 + ty;
    tile[row][tx] = f2bf_rte(in[(size_t)(r0 + row) * 1024 + c0 + tx]);
  }
  __syncthreads();
  for (int rr = 0; rr < 16; ++rr) {
    int row = rr * 4 + ty;
    o[(size_t)(c0 + row) * 1024 + r0 + tx] = tile[tx][row];
  }
}

// ---------------- transpose V [bh][2048][64] -> Vt[bh][64][2048] ----------------
__global__ __launch_bounds__(256) void k_transpose_v(const u16* __restrict__ V,
                                                     u16* __restrict__ Vt) {
  __shared__ u16 tile[64][65];
  const int t = threadIdx.x, tx = t & 63, ty = t >> 6;
  const int j0 = blockIdx.x * 64;
  const int bh = blockIdx.y;
  const u16* src = V + (size_t)bh * 2048 * 64;
  u16* dst = Vt + (size_t)bh * 64 * 2048;
  for (int rr = 0; rr < 16; ++rr) {
    int row = rr * 4 + ty;
    tile[row][tx] = src[(size_t)(j0 + row) * 64 + tx];
  }
  __syncthreads();
  for (int rr = 0; rr < 16; ++rr) {
    int d = rr * 4 + ty;
    dst[(size_t)d * 2048 + j0 + tx] = tile[tx][d];
  }
}

// ---------------- fused QKV GEMM: dbuf LDS + swizzled source + XCD swizzle ----------------
// Q pre-scaled by 0.125*log2(e) (exp2-domain attention). K gets pos added.
__global__ __launch_bounds__(256) void k_qkv_gemm(const u16* __restrict__ X,
                                                  const u16* __restrict__ WT,
                                                  const float* __restrict__ pos,
                                                  u16* __restrict__ Qh,
                                                  u16* __restrict__ Kh,
                                                  u16* __restrict__ Vh) {
  __shared__ u16 As[2][4096];
  __shared__ u16 Bs[2][4096];
  const int t = threadIdx.x;
  const int lane = t & 63, wid = t >> 6;
  const int wr = wid >> 1, wc = wid & 1;
  const int g = lane >> 4, lr = lane & 15;
  const int lin = blockIdx.y * 24 + blockIdx.x;
  const int swz = (lin & 7) * 96 + (lin >> 3);
  const int m0 = (swz / 24) * 128, n0 = (swz % 24) * 128;

  const int srcRow = t >> 2;
  const int srcKsw = ((t & 3) * 8) ^ (((t >> 3) & 3) << 3);
  const u16* aSrc = &X[(size_t)(m0 + srcRow) * 1024 + srcKsw];
  const u16* bSrc = &WT[(size_t)(n0 + srcRow) * 1024 + srcKsw];

  const int csw = (g * 8) ^ (((lr >> 1) & 3) << 3);

  f32x4 acc[4][4] = {};

#define QKV_STAGE(buf, k0)                                   \
  {                                                          \
    gload16(aSrc + (k0), &As[buf][wid * 512]);               \
    gload16(aSrc + 65536 + (k0), &As[buf][wid * 512 + 2048]);\
    gload16(bSrc + (k0), &Bs[buf][wid * 512]);               \
    gload16(bSrc + 65536 + (k0), &Bs[buf][wid * 512 + 2048]);\
  }

  QKV_STAGE(0, 0);
  int cur = 0;
  for (int k0 = 0; k0 < 1024; k0 += 32) {
    __syncthreads();
    if (k0 < 992) QKV_STAGE(cur ^ 1, k0 + 32);
    s16x8 a[4], b[4];
#pragma unroll
    for (int mi = 0; mi < 4; ++mi)
      a[mi] = *(const s16x8*)&As[cur][(wr * 64 + mi * 16 + lr) * 32 + csw];
#pragma unroll
    for (int nj = 0; nj < 4; ++nj)
      b[nj] = *(const s16x8*)&Bs[cur][(wc * 64 + nj * 16 + lr) * 32 + csw];
#pragma unroll
    for (int mi = 0; mi < 4; ++mi)
#pragma unroll
      for (int nj = 0; nj < 4; ++nj)
        acc[mi][nj] = MFMA(a[mi], b[nj], acc[mi][nj]);
    cur ^= 1;
  }
#undef QKV_STAGE

  const float QSCALE = 0.125f * 1.44269504f;
  for (int mi = 0; mi < 4; ++mi) {
    for (int nj = 0; nj < 4; ++nj) {
      const int n_g = n0 + wc * 64 + nj * 16 + lr;
      const int buf = n_g >> 10;       // 0=Q 1=K 2=V
      const int col = n_g & 1023;
      const int h = col >> 6, d = col & 63;
      u16* dst = (buf == 0) ? Qh : ((buf == 1) ? Kh : Vh);
      for (int r = 0; r < 4; ++r) {
        const int row = m0 + wr * 64 + mi * 16 + g * 4 + r;  // 0..4095
        const int b = row >> 11, n = row & 2047;
        float v = acc[mi][nj][r];
        if (buf == 1) v += pos[(size_t)row * 1024 + col];
        if (buf == 0) v *= QSCALE;
        dst[(size_t)((b * 16 + h) * 2048 + n) * 64 + d] = f2bf_rte(v);
      }
    }
  }
}

// ---------------- flash attention: swapped QK^T, in-register P (no P LDS) ----------------
__global__ __launch_bounds__(256, 2) void k_attn(const u16* __restrict__ Qh,
                                                 const u16* __restrict__ Kh,
                                                 const u16* __restrict__ Vt,
                                                 u16* __restrict__ Oh) {
  const int t = threadIdx.x, lane = t & 63, wid = t >> 6;
  const int g = lane >> 4, lr = lane & 15;
  const int hid = blockIdx.x;
  const int lid = (hid & 7) * 64 + (hid >> 3);   // bijective XCD swizzle (512 % 8 == 0)
  const int bh = lid >> 4, itile = lid & 15;
  const int i0 = itile * 128 + wid * 16;         // wave rows: i0..i0+15 and i0+64..i0+79

  __shared__ char Ks[2][8192];     // K tile double buffer (swizzled)
  __shared__ char Vs[2][8192];     // V tile double buffer (swizzled)

  const u16* Qp = Qh + (size_t)bh * 2048 * 64;
  const u16* Kp = Kh + (size_t)bh * 2048 * 64;
  const u16* Vp = Vt + (size_t)bh * 64 * 2048;

  s16x8 aq0[2], aq1[2];
  aq0[0] = *(const s16x8*)&Qp[(size_t)(i0 + lr) * 64 + g * 8];
  aq0[1] = *(const s16x8*)&Qp[(size_t)(i0 + lr) * 64 + 32 + g * 8];
  aq1[0] = *(const s16x8*)&Qp[(size_t)(i0 + 64 + lr) * 64 + g * 8];
  aq1[1] = *(const s16x8*)&Qp[(size_t)(i0 + 64 + lr) * 64 + 32 + g * 8];

  f32x4 oa0[4] = {}, oa1[4] = {};
  float m0s = -1e30f, m1s = -1e30f, l0s = 0.f, l1s = 0.f;

  // cooperative staging setup (256 threads stage 8KB K + 8KB V per tile)
  const int srow = t >> 3;
  const int sch = (t & 7) * 16;
  const int swz = (srow & 7) << 4;
  const int sb0 = (srow * 128 + sch) ^ swz;
  const int sb1 = ((srow + 32) * 128 + sch) ^ swz;
  const u16* kB0 = &Kp[(size_t)srow * 64 + (sch >> 1)];
  const u16* kB1 = &Kp[(size_t)(srow + 32) * 64 + (sch >> 1)];
  const u16* vB0 = &Vp[(size_t)srow * 2048 + (sch >> 1)];
  const u16* vB1 = &Vp[(size_t)(srow + 32) * 2048 + (sch >> 1)];

  s16x8 kr0 = *(const s16x8*)kB0;
  s16x8 kr1 = *(const s16x8*)kB1;
  s16x8 vr0 = *(const s16x8*)vB0;
  s16x8 vr1 = *(const s16x8*)vB1;
  *(s16x8*)(Ks[0] + sb0) = kr0;
  *(s16x8*)(Ks[0] + sb1) = kr1;
  *(s16x8*)(Vs[0] + sb0) = vr0;
  *(s16x8*)(Vs[0] + sb1) = vr1;
  __syncthreads();

  const int src0 = ((g & 1) * 2) * 16 + lr;  // source lane for pa words 0,1
  const int src1 = src0 + 16;                // source lane for pa words 2,3

  for (int tt = 0; tt < 32; ++tt) {
    const int cur = tt & 1;
    if (tt < 31) {
      const size_t j1 = (size_t)(tt + 1) * 64;
      kr0 = *(const s16x8*)(kB0 + j1 * 64);
      kr1 = *(const s16x8*)(kB1 + j1 * 64);
      vr0 = *(const s16x8*)(vB0 + j1);
      vr1 = *(const s16x8*)(vB1 + j1);
    }
    const char* Kc = Ks[cur];
    const char* Vc = Vs[cur];

    // ---- QK^T, SWAPPED operands: s[jf][r] = S[q=lr][j=jf*16+g*4+r] ----
    f32x4 s0[4] = {}, s1[4] = {};
    __builtin_amdgcn_s_setprio(1);
#pragma unroll
    for (int jf = 0; jf < 4; ++jf) {
      const int row = jf * 16 + lr;
      const int bw = (row & 7) << 4;
      s16x8 bk0 = *(const s16x8*)(Kc + ((row * 128 + g * 16) ^ bw));
      s16x8 bk1 = *(const s16x8*)(Kc + ((row * 128 + 64 + g * 16) ^ bw));
      s0[jf] = MFMA(bk0, aq0[0], s0[jf]);
      s0[jf] = MFMA(bk1, aq0[1], s0[jf]);
      s1[jf] = MFMA(bk0, aq1[0], s1[jf]);
      s1[jf] = MFMA(bk1, aq1[1], s1[jf]);
    }
    __builtin_amdgcn_s_setprio(0);

    // ---- lane-local defer-max check (T13) ----
    float tl0 = s0[0][0], tl1 = s1[0][0];
#pragma unroll
    for (int jf = 0; jf < 4; ++jf)
#pragma unroll
      for (int r = 0; r < 4; ++r) {
        if (jf | r) {
          tl0 = fmaxf(tl0, s0[jf][r]);
          tl1 = fmaxf(tl1, s1[jf][r]);
        }
      }
    int ok = (tl0 <= m0s + 8.f) & (tl1 <= m1s + 8.f);
    if (!__all(ok)) {
      float tm0 = fmaxf(tl0, __shfl_xor(tl0, 16, 64));
      tm0 = fmaxf(tm0, __shfl_xor(tm0, 32, 64));
      float tm1 = fmaxf(tl1, __shfl_xor(tl1, 16, 64));
      tm1 = fmaxf(tm1, __shfl_xor(tm1, 32, 64));
      float mn0 = fmaxf(m0s, tm0), mn1 = fmaxf(m1s, tm1);
      float al0 = __builtin_amdgcn_exp2f(m0s - mn0);
      float al1 = __builtin_amdgcn_exp2f(m1s - mn1);
      l0s *= al0; m0s = mn0;
      l1s *= al1; m1s = mn1;
#pragma unroll
      for (int r = 0; r < 4; ++r) {
        float ab0 = __shfl(al0, g * 4 + r, 64);
        float ab1 = __shfl(al1, g * 4 + r, 64);
#pragma unroll
        for (int df = 0; df < 4; ++df) {
          oa0[df][r] *= ab0;
          oa1[df][r] *= ab1;
        }
      }
    }

    // ---- exp2 (log2-domain) + per-lane partial l ----
#pragma unroll
    for (int jf = 0; jf < 4; ++jf)
#pragma unroll
      for (int r = 0; r < 4; ++r) {
        float p0 = __builtin_amdgcn_exp2f(s0[jf][r] - m0s);
        float p1 = __builtin_amdgcn_exp2f(s1[jf][r] - m1s);
        s0[jf][r] = p0; l0s += p0;
        s1[jf][r] = p1; l1s += p1;
      }

    // ---- pack P to bf16 pairs in-register ----
    u32 pk0[4][2], pk1[4][2];
#pragma unroll
    for (int jf = 0; jf < 4; ++jf) {
      asm("v_cvt_pk_bf16_f32 %0, %1, %2" : "=v"(pk0[jf][0]) : "v"(s0[jf][0]), "v"(s0[jf][1]));
      asm("v_cvt_pk_bf16_f32 %0, %1, %2" : "=v"(pk0[jf][1]) : "v"(s0[jf][2]), "v"(s0[jf][3]));
      asm("v_cvt_pk_bf16_f32 %0, %1, %2" : "=v"(pk1[jf][0]) : "v"(s1[jf][0]), "v"(s1[jf][1]));
      asm("v_cvt_pk_bf16_f32 %0, %1, %2" : "=v"(pk1[jf][1]) : "v"(s1[jf][2]), "v"(s1[jf][3]));
    }

    // ---- build PV A-fragments via cross-lane shuffles (no LDS) ----
    // pa[c] word w <- lane ((g&1)*2+(w>>1))*16+lr, register pk[2c+(g>>1)][w&1]
    s16x8 pa0[2], pa1[2];
#pragma unroll
    for (int c = 0; c < 2; ++c) {
      u32 a0 = (u32)__shfl((int)pk0[2 * c][0], src0, 64);
      u32 a1 = (u32)__shfl((int)pk0[2 * c][1], src0, 64);
      u32 a2 = (u32)__shfl((int)pk0[2 * c][0], src1, 64);
      u32 a3 = (u32)__shfl((int)pk0[2 * c][1], src1, 64);
      u32 b0 = (u32)__shfl((int)pk0[2 * c + 1][0], src0, 64);
      u32 b1 = (u32)__shfl((int)pk0[2 * c + 1][1], src0, 64);
      u32 b2 = (u32)__shfl((int)pk0[2 * c + 1][0], src1, 64);
      u32 b3 = (u32)__shfl((int)pk0[2 * c + 1][1], src1, 64);
      u32 w[4];
      w[0] = (g & 2) ? b0 : a0;
      w[1] = (g & 2) ? b1 : a1;
      w[2] = (g & 2) ? b2 : a2;
      w[3] = (g & 2) ? b3 : a3;
      __builtin_memcpy(&pa0[c], w, 16);
      u32 c0 = (u32)__shfl((int)pk1[2 * c][0], src0, 64);
      u32 c1 = (u32)__shfl((int)pk1[2 * c][1], src0, 64);
      u32 c2 = (u32)__shfl((int)pk1[2 * c][0], src1, 64);
      u32 c3 = (u32)__shfl((int)pk1[2 * c][1], src1, 64);
      u32 d0 = (u32)__shfl((int)pk1[2 * c + 1][0], src0, 64);
      u32 d1 = (u32)__shfl((int)pk1[2 * c + 1][1], src0, 64);
      u32 d2 = (u32)__shfl((int)pk1[2 * c + 1][0], src1, 64);
      u32 d3 = (u32)__shfl((int)pk1[2 * c + 1][1], src1, 64);
      u32 x[4];
      x[0] = (g & 2) ? d0 : c0;
      x[1] = (g & 2) ? d1 : c1;
      x[2] = (g & 2) ? d2 : c2;
      x[3] = (g & 2) ? d3 : c3;
      __builtin_memcpy(&pa1[c], x, 16);
    }

    // ---- PV from LDS V + in-register P ----
    __builtin_amdgcn_s_setprio(1);
#pragma unroll
    for (int df = 0; df < 4; ++df) {
      const int row = df * 16 + lr;
      const int bw = (row & 7) << 4;
      s16x8 bv0 = *(const s16x8*)(Vc + ((row * 128 + g * 16) ^ bw));
      s16x8 bv1 = *(const s16x8*)(Vc + ((row * 128 + 64 + g * 16) ^ bw));
      oa0[df] = MFMA(pa0[0], bv0, oa0[df]);
      oa0[df] = MFMA(pa0[1], bv1, oa0[df]);
      oa1[df] = MFMA(pa1[0], bv0, oa1[df]);
      oa1[df] = MFMA(pa1[1], bv1, oa1[df]);
    }
    __builtin_amdgcn_s_setprio(0);

    // ---- write next K/V tile into the other buffer, then sync ----
    if (tt < 31) {
      char* Kn = Ks[cur ^ 1];
      char* Vn = Vs[cur ^ 1];
      *(s16x8*)(Kn + sb0) = kr0;
      *(s16x8*)(Kn + sb1) = kr1;
      *(s16x8*)(Vn + sb0) = vr0;
      *(s16x8*)(Vn + sb1) = vr1;
    }
    __syncthreads();
  }

  // final l: cross-g reduce (lanes lr,lr+16,lr+32,lr+48 hold partials of q-row lr)
  l0s += __shfl_xor(l0s, 16, 64);
  l0s += __shfl_xor(l0s, 32, 64);
  l1s += __shfl_xor(l1s, 16, 64);
  l1s += __shfl_xor(l1s, 32, 64);

  float lb0[4], lb1[4];
#pragma unroll
  for (int r = 0; r < 4; ++r) {
    lb0[r] = __shfl(l0s, g * 4 + r, 64);
    lb1[r] = __shfl(l1s, g * 4 + r, 64);
  }

  u16* Op = Oh + (size_t)bh * 2048 * 64;
#pragma unroll
  for (int df = 0; df < 4; ++df)
#pragma unroll
    for (int r = 0; r < 4; ++r) {
      const int row0 = i0 + g * 4 + r;
      Op[(size_t)row0 * 64 + df * 16 + lr] = f2bf_rte(oa0[df][r] / lb0[r]);
      Op[(size_t)(row0 + 64) * 64 + df * 16 + lr] = f2bf_rte(oa1[df][r] / lb1[r]);
    }
}

// ---------------- out GEMM: dbuf LDS + swizzled source + XCD swizzle ----------------
__global__ __launch_bounds__(256) void k_out_gemm(const u16* __restrict__ Oh,
                                                  const u16* __restrict__ WTo,
                                                  const float* __restrict__ bo,
                                                  const float* __restrict__ qs,
                                                  float* __restrict__ X) {
  __shared__ u16 As[2][4096];
  __shared__ u16 Bs[2][4096];
  const int t = threadIdx.x;
  const int lane = t & 63, wid = t >> 6;
  const int wr = wid >> 1, wc = wid & 1;
  const int g = lane >> 4, lr = lane & 15;
  const int lin = blockIdx.y * 8 + blockIdx.x;
  const int swz = (lin & 7) * 32 + (lin >> 3);
  const int m0 = (swz / 8) * 128, n0 = (swz % 8) * 128;

  const int srcRow = t >> 2;
  const int srcKsw = ((t & 3) * 8) ^ (((t >> 3) & 3) << 3);
  const int rg = m0 + srcRow, bb0 = rg >> 11, nn0 = rg & 2047;
  const int rg2 = rg + 64, bb2 = rg2 >> 11, nn2 = rg2 & 2047;
  const u16* bSrc = &WTo[(size_t)(n0 + srcRow) * 1024 + srcKsw];
  const int csw = (g * 8) ^ (((lr >> 1) & 3) << 3);

  f32x4 acc[4][4] = {};

#define OUT_STAGE(buf, k0)                                                        \
  {                                                                               \
    const int h_ = (k0) >> 6, d_ = ((k0) & 63) + srcKsw;                          \
    gload16(&Oh[((size_t)(bb0 * 16 + h_) * 2048 + nn0) * 64 + d_],                \
            &As[buf][wid * 512]);                                                 \
    gload16(&Oh[((size_t)(bb2 * 16 + h_) * 2048 + nn2) * 64 + d_],                \
            &As[buf][wid * 512 + 2048]);                                          \
    gload16(bSrc + (k0), &Bs[buf][wid * 512]);                                    \
    gload16(bSrc + 65536 + (k0), &Bs[buf][wid * 512 + 2048]);                     \
  }

  OUT_STAGE(0, 0);
  int cur = 0;
  for (int k0 = 0; k0 < 1024; k0 += 32) {
    __syncthreads();
    if (k0 < 992) OUT_STAGE(cur ^ 1, k0 + 32);
    s16x8 a[4], b[4];
#pragma unroll
    for (int mi = 0; mi < 4; ++mi)
      a[mi] = *(const s16x8*)&As[cur][(wr * 64 + mi * 16 + lr) * 32 + csw];
#pragma unroll
    for (int nj = 0; nj < 4; ++nj)
      b[nj] = *(const s16x8*)&Bs[cur][(wc * 64 + nj * 16 + lr) * 32 + csw];
#pragma unroll
    for (int mi = 0; mi < 4; ++mi)
#pragma unroll
      for (int nj = 0; nj < 4; ++nj)
        acc[mi][nj] = MFMA(a[mi], b[nj], acc[mi][nj]);
    cur ^= 1;
  }
#undef OUT_STAGE

  for (int mi = 0; mi < 4; ++mi) {
    for (int nj = 0; nj < 4; ++nj) {
      const int col = n0 + wc * 64 + nj * 16 + lr;
      for (int r = 0; r < 4; ++r) {
        const int row = m0 + wr * 64 + mi * 16 + g * 4 + r;
        float v = acc[mi][nj][r] + bo[col] + qs[(size_t)row * 1024 + col];
        X[(size_t)row * 1024 + col] = v;
      }
    }
  }
}

// ---------------- LayerNorm rows of 1024 (f32 in, f32 out) ----------------
__global__ __launch_bounds__(256) void k_ln(const float* __restrict__ X,
                                            const float* __restrict__ gg,
                                            const float* __restrict__ bb,
                                            float* __restrict__ out) {
  const int row = blockIdx.x, t = threadIdx.x;
  const int wid = t >> 6, lane = t & 63;
  const float* xr = X + (size_t)row * 1024;
  f32x4 x = *(const f32x4*)&xr[t * 4];
  float s1 = x[0] + x[1] + x[2] + x[3];
  float s2 = x[0] * x[0] + x[1] * x[1] + x[2] * x[2] + x[3] * x[3];
  for (int off = 32; off > 0; off >>= 1) {
    s1 += __shfl_down(s1, off, 64);
    s2 += __shfl_down(s2, off, 64);
  }
  __shared__ float red[2][4];
  if (lane == 0) { red[0][wid] = s1; red[1][wid] = s2; }
  __syncthreads();
  s1 = red[0][0] + red[0][1] + red[0][2] + red[0][3];
  s2 = red[1][0] + red[1][1] + red[1][2] + red[1][3];
  const float mu = s1 * (1.f / 1024.f);
  const float var = s2 * (1.f / 1024.f) - mu * mu;
  const float rstd = rsqrtf(var + 1e-5f);
  f32x4 gv = *(const f32x4*)&gg[t * 4];
  f32x4 bv = *(const f32x4*)&bb[t * 4];
  f32x4 ov;
  for (int i = 0; i < 4; ++i) ov[i] = (x[i] - mu) * rstd * gv[i] + bv[i];
  *(f32x4*)&out[(size_t)row * 1024 + t * 4] = ov;
}

extern "C" void kernel_launch(void* const* d_in, const int* in_sizes, int n_in,
                              void* d_out, int out_size, void* d_ws, size_t ws_size,
                              hipStream_t stream) {
  (void)in_sizes; (void)n_in; (void)out_size; (void)ws_size;
  const float* q_s = (const float*)d_in[0];
  const float* pos = (const float*)d_in[1];
  const float* Wq = (const float*)d_in[2];
  const float* Wk = (const float*)d_in[3];
  const float* Wv = (const float*)d_in[4];
  const float* Wo = (const float*)d_in[5];
  const float* bo = (const float*)d_in[6];
  const float* lng = (const float*)d_in[7];
  const float* lnb = (const float*)d_in[8];
  float* out = (float*)d_out;

  u16* ws = (u16*)d_ws;
  const size_t MB1 = 1024 * 1024;  // elements
  u16* WT  = ws;                   // 4 x 1M bf16 (Wq^T,Wk^T,Wv^T,Wo^T)
  u16* Xbf = ws + 4 * MB1;         // q_s as bf16
  u16* Qh  = Xbf + 4 * MB1;        // [32][2048][64]
  u16* Kh  = Qh + 4 * MB1;
  u16* Vh  = Kh + 4 * MB1;
  u16* Vt  = Vh + 4 * MB1;         // [32][64][2048]
  u16* Oh  = Vt + 4 * MB1;         // [32][2048][64]
  float* Xb = (float*)Qh;          // f32 pre-LN x, aliases Qh+Kh (dead after attn)

  dim3 blk(256);
  k_cvt<<<dim3(2048), blk, 0, stream>>>(q_s, Xbf, 4 * MB1 / 8);
  k_transpose_w<<<dim3(16, 16, 4), blk, 0, stream>>>(Wq, Wk, Wv, Wo, WT);
  k_qkv_gemm<<<dim3(24, 32), blk, 0, stream>>>(Xbf, WT, pos, Qh, Kh, Vh);
  k_transpose_v<<<dim3(32, 32), blk, 0, stream>>>(Vh, Vt);
  k_attn<<<dim3(512), blk, 0, stream>>>(Qh, Kh, Vt, Oh);
  k_out_gemm<<<dim3(8, 32), blk, 0, stream>>>(Oh, WT + 3 * MB1, bo, q_s, Xb);
  k_ln<<<4096, blk, 0, stream>>>(Xb, lng, lnb, out);
}